// Round 8
// baseline (159.302 us; speedup 1.0000x reference)
//
#include <hip/hip_runtime.h>
#include <hip/hip_bf16.h>

#define N_TOK 8192
#define D_IN  1024
#define DK    128
#define NT    256   // number of 32-row q tiles (== number of 32-row kv tiles)

typedef __attribute__((ext_vector_type(8))) short short8;
typedef __attribute__((ext_vector_type(4))) float f32x4;

static __device__ __forceinline__ unsigned short f2bf(float f) {
    __hip_bfloat16 h = __float2bfloat16(f);
    return __builtin_bit_cast(unsigned short, h);
}

static __device__ __forceinline__ void gl_lds16(const void* g, void* l) {
    __builtin_amdgcn_global_load_lds(
        (const __attribute__((address_space(1))) void*)g,
        (__attribute__((address_space(3))) void*)l, 16, 0, 0);
}

// ---------------- one-time W transpose: W[k][n] f32 -> Wt[n][k] bf16 ----------------
__global__ __launch_bounds__(256) void wtrans_kernel(
    const float* __restrict__ Wq, const float* __restrict__ Wk,
    const float* __restrict__ Wv, unsigned short* __restrict__ Wt)
{
    __shared__ unsigned short T[64][72];
    const int proj = blockIdx.y;
    const float* W = (proj == 0) ? Wq : (proj == 1) ? Wk : Wv;
    unsigned short* out = Wt + (size_t)proj * DK * D_IN;
    const int k0 = (blockIdx.x & 15) * 64, n0 = (blockIdx.x >> 4) * 64;
    const int tid = threadIdx.x;
    #pragma unroll
    for (int i = 0; i < 4; i++) {
        int e = tid + i * 256;
        int r = e >> 4, c4 = e & 15;
        float4 v = *reinterpret_cast<const float4*>(&W[(size_t)(k0 + r) * DK + n0 + c4 * 4]);
        T[c4 * 4 + 0][r] = f2bf(v.x);
        T[c4 * 4 + 1][r] = f2bf(v.y);
        T[c4 * 4 + 2][r] = f2bf(v.z);
        T[c4 * 4 + 3][r] = f2bf(v.w);
    }
    __syncthreads();
    #pragma unroll
    for (int i = 0; i < 4; i++) {
        int e = tid + i * 256;
        int r = e >> 4, c4 = e & 15;
        *reinterpret_cast<ushort4*>(&out[(size_t)(n0 + r) * D_IN + k0 + c4 * 4]) =
            *reinterpret_cast<const ushort4*>(&T[r][c4 * 4]);
    }
}

// ---------------- fused QKV projection, 512 blocks (row-tile x col-half) --------
// block = (rt, half): rows [rt*32,+32), cols [half*192,+192). 4 waves x 48 cols.
// X reg-staged f32->bf16 into double-buffered LDS; W from bf16 Wt (L2-resident).
// Q row-major; K row-major 16B-block-swizzled; V transposed+swizzled.
__global__ __launch_bounds__(256) void proj_fused(
    const float* __restrict__ X, const unsigned short* __restrict__ Wt,
    const float* __restrict__ bq, const float* __restrict__ bk,
    const float* __restrict__ bv,
    unsigned short* __restrict__ Qb, unsigned short* __restrict__ Kb,
    unsigned short* __restrict__ Vt)
{
    __shared__ unsigned short Xs[2][32][72];   // 32 rows x 64 k bf16, pad 72

    const int tid = threadIdx.x;
    const int wid = tid >> 6, lane = tid & 63;
    const int g = lane >> 4, r16 = lane & 15;
    const int mb   = (blockIdx.x >> 1) * 32;
    const int half = blockIdx.x & 1;

    float4 xr[2];
    auto XLOAD = [&](int k0) {
        #pragma unroll
        for (int i = 0; i < 2; i++) {
            int e = tid + i * 256;      // 512 float4s = 32x64 f32
            int r = e >> 4, c4 = e & 15;
            xr[i] = *reinterpret_cast<const float4*>(
                &X[(size_t)(mb + r) * D_IN + k0 + c4 * 4]);
        }
    };
    auto XWRITE = [&](int buf) {
        #pragma unroll
        for (int i = 0; i < 2; i++) {
            int e = tid + i * 256;
            int r = e >> 4, c4 = e & 15;
            ushort4 h;
            h.x = f2bf(xr[i].x); h.y = f2bf(xr[i].y);
            h.z = f2bf(xr[i].z); h.w = f2bf(xr[i].w);
            *reinterpret_cast<ushort4*>(&Xs[buf][r][c4 * 4]) = h;
        }
    };

    f32x4 acc[2][3] = {};   // [mi: 16-row frag][ni], wave cols nn = half*192+wid*48+ni*16

    XLOAD(0); XWRITE(0);
    __syncthreads();
    for (int s = 0; s < 16; ++s) {
        const int k0 = s * 64;
        const int cur = s & 1;
        if (s + 1 < 16) XLOAD(k0 + 64);
        #pragma unroll
        for (int kk = 0; kk < 64; kk += 32) {
            short8 af[2], bfr[3];
            #pragma unroll
            for (int mi = 0; mi < 2; mi++)
                af[mi] = *reinterpret_cast<const short8*>(&Xs[cur][mi * 16 + r16][kk + g * 8]);
            #pragma unroll
            for (int ni = 0; ni < 3; ni++) {
                int nn = half * 192 + wid * 48 + ni * 16;
                int pj = nn >> 7;
                bfr[ni] = *reinterpret_cast<const short8*>(
                    &Wt[((size_t)pj * DK + (nn & 127) + r16) * D_IN + k0 + kk + g * 8]);
            }
            __builtin_amdgcn_s_setprio(1);
            #pragma unroll
            for (int mi = 0; mi < 2; mi++)
                #pragma unroll
                for (int ni = 0; ni < 3; ni++)
                    acc[mi][ni] = __builtin_amdgcn_mfma_f32_16x16x32_bf16(
                        af[mi], bfr[ni], acc[mi][ni], 0, 0, 0);
            __builtin_amdgcn_s_setprio(0);
        }
        if (s + 1 < 16) XWRITE((s + 1) & 1);
        __syncthreads();
    }

    // ---- epilogue ----
    #pragma unroll
    for (int ni = 0; ni < 3; ni++) {
        int nn = half * 192 + wid * 48 + ni * 16;
        int pj = nn >> 7;
        int n = (nn & 127) + r16;
        const float* bias = (pj == 0) ? bq : (pj == 1) ? bk : bv;
        float b = bias[n];
        if (pj < 2) {
            unsigned short* out = (pj == 0) ? Qb : Kb;
            #pragma unroll
            for (int mi = 0; mi < 2; mi++)
                #pragma unroll
                for (int e = 0; e < 4; e++) {
                    int m = mb + mi * 16 + g * 4 + e;
                    int nc = n;
                    if (pj == 1)   // K swizzle: 16B block ^= (kv&7)
                        nc = ((((n >> 3) ^ (m & 7)) << 3) | (n & 7));
                    out[(size_t)m * DK + nc] = f2bf(acc[mi][ni][e] + b);
                }
        } else {
            #pragma unroll
            for (int mi = 0; mi < 2; mi++) {
                int m0 = mb + mi * 16 + g * 4;
                int mblk = (((m0 & 31) >> 3) ^ (n & 3));
                int mp = (m0 & ~31) | (mblk << 3) | (m0 & 7);
                ushort4 h;
                h.x = f2bf(acc[mi][ni][0] + b);
                h.y = f2bf(acc[mi][ni][1] + b);
                h.z = f2bf(acc[mi][ni][2] + b);
                h.w = f2bf(acc[mi][ni][3] + b);
                *reinterpret_cast<ushort4*>(&Vt[(size_t)n * N_TOK + mp]) = h;
            }
        }
    }
}

// ---------------- causal flash attention: 32-row waves, no P-LDS, bf16 partials --
// grid = (64 q-blocks, max_chunks). Block (qb,c): q rows [qb*128,+128), kv tiles
// [c*ct, min((c+1)*ct, 4qb+4)). 4 waves of 32 q-rows share LDS K/V (32 KB only:
// P transposed IN-REGISTER via cvt_pk + 4-lane-group shfl). Counted-vmcnt dbuf.
__global__ __launch_bounds__(256, 4) void attn_partial(
    const unsigned short* __restrict__ Qb, const unsigned short* __restrict__ Ksw,
    const unsigned short* __restrict__ Vsw,
    unsigned short* __restrict__ OpartH, float* __restrict__ Mpart,
    float* __restrict__ Lpart,
    float* __restrict__ O, int chunk_tiles, int max_chunks, int direct)
{
    __shared__ unsigned short Klds[2][32][128];   // 16 KB
    __shared__ unsigned short Vlds[2][128][32];   // 16 KB

    const int qb = blockIdx.x, c = blockIdx.y;
    const int j0 = c * chunk_tiles;
    const int jmax = 4 * qb + 4;
    const int jend = min(j0 + chunk_tiles, jmax);
    if (j0 >= jend) return;
    const int nt = jend - j0;

    const int tid = threadIdx.x;
    const int wid = tid >> 6, lane = tid & 63;
    const int g = lane >> 4, r16 = lane & 15;
    const int t = qb * 4 + wid;     // this wave's 32-row q tile index
    const int qw = t * 32;
    const float scale2 = 0.08838834764831845f * 1.4426950408889634f; // /sqrt(dk)*log2e

    auto STAGE = [&](int buf, int kvb) {   // exactly 4 gl_lds per thread
        #pragma unroll
        for (int s = 0; s < 2; s++) {                  // K: 8KB linear copy
            int ob = ((wid * 2 + s) << 10);
            gl_lds16((const char*)Ksw + ((size_t)kvb << 8) + ob + (lane << 4),
                     (char*)&Klds[buf][0][0] + ob);
        }
        #pragma unroll
        for (int s = 0; s < 2; s++) {                  // V: 128 rows x 64B
            int ob = ((wid * 2 + s) << 10);
            int o = ob + (lane << 4);
            int d = o >> 6, cb = o & 63;
            gl_lds16((const char*)Vsw + (((size_t)d * N_TOK + kvb) << 1) + cb,
                     (char*)&Vlds[buf][0][0] + ob);
        }
    };

    // Q fragments (B-operand): col=q=mi*16+r16, k=d
    short8 qf[2][4];
    #pragma unroll
    for (int mi = 0; mi < 2; mi++)
        #pragma unroll
        for (int kd = 0; kd < 4; kd++)
            qf[mi][kd] = *reinterpret_cast<const short8*>(
                &Qb[(size_t)(qw + mi * 16 + r16) * DK + kd * 32 + g * 8]);

    f32x4 o_acc[2][8] = {};                  // O^T: [q-frag mi][d-frag df]
    float m_run[2] = {-1e30f, -1e30f}, l_run[2] = {0.f, 0.f};

    STAGE(0, j0 * 32);

    int cur = 0;
    for (int it = 0; it < nt; ++it) {
        const int kvb = (j0 + it) * 32;
        if (it + 1 < nt) {
            STAGE(cur ^ 1, kvb + 32);
            asm volatile("s_waitcnt vmcnt(4)" ::: "memory");   // tile it landed
        } else {
            asm volatile("s_waitcnt vmcnt(0)" ::: "memory");
        }
        __builtin_amdgcn_sched_barrier(0);
        __builtin_amdgcn_s_barrier();
        __builtin_amdgcn_sched_barrier(0);

        const unsigned short* Kl = &Klds[cur][0][0];
        const unsigned short* Vl = &Vlds[cur][0][0];

        // ---- S^T = K Q^T from LDS (swizzled reads) ----
        f32x4 st[2][2] = {};                 // [ni=kv frag][mi=q frag]
        #pragma unroll
        for (int kd = 0; kd < 4; kd++) {
            int swb = ((((kd << 2) | g) ^ (r16 & 7)) << 3);
            short8 kf0 = *reinterpret_cast<const short8*>(Kl + r16 * 128 + swb);
            short8 kf1 = *reinterpret_cast<const short8*>(Kl + (16 + r16) * 128 + swb);
            __builtin_amdgcn_s_setprio(1);
            st[0][0] = __builtin_amdgcn_mfma_f32_16x16x32_bf16(kf0, qf[0][kd], st[0][0], 0, 0, 0);
            st[0][1] = __builtin_amdgcn_mfma_f32_16x16x32_bf16(kf0, qf[1][kd], st[0][1], 0, 0, 0);
            st[1][0] = __builtin_amdgcn_mfma_f32_16x16x32_bf16(kf1, qf[0][kd], st[1][0], 0, 0, 0);
            st[1][1] = __builtin_amdgcn_mfma_f32_16x16x32_bf16(kf1, qf[1][kd], st[1][1], 0, 0, 0);
            __builtin_amdgcn_s_setprio(0);
        }

        // ---- online softmax (exp2 domain) + in-register P transpose ----
        const bool anymask = (kvb + 31 > qw);
        short8 pb[2];
        #pragma unroll
        for (int mi = 0; mi < 2; mi++) {
            const int qrow = qw + mi * 16 + r16;
            float s[2][4];
            #pragma unroll
            for (int ni = 0; ni < 2; ni++)
                #pragma unroll
                for (int e = 0; e < 4; e++) {
                    float v = st[ni][mi][e] * scale2;
                    if (anymask && (kvb + ni * 16 + g * 4 + e > qrow)) v = -1e30f;
                    s[ni][e] = v;
                }
            float lm = fmaxf(fmaxf(fmaxf(s[0][0], s[0][1]), fmaxf(s[0][2], s[0][3])),
                             fmaxf(fmaxf(s[1][0], s[1][1]), fmaxf(s[1][2], s[1][3])));
            lm = fmaxf(lm, __shfl_xor(lm, 16));
            lm = fmaxf(lm, __shfl_xor(lm, 32));
            // T13 defer-rescale: keep old max while growth <= 8 (P bounded by 256)
            bool nog = __all(lm - m_run[mi] <= 8.0f);
            float mnew = nog ? m_run[mi] : fmaxf(m_run[mi], lm);
            float ps[2][4];
            #pragma unroll
            for (int ni = 0; ni < 2; ni++)
                #pragma unroll
                for (int e = 0; e < 4; e++)
                    ps[ni][e] = exp2f(s[ni][e] - mnew);
            float ls = ((ps[0][0] + ps[0][1]) + (ps[0][2] + ps[0][3]))
                     + ((ps[1][0] + ps[1][1]) + (ps[1][2] + ps[1][3]));
            ls += __shfl_xor(ls, 16);
            ls += __shfl_xor(ls, 32);
            if (nog) {
                l_run[mi] += ls;
            } else {
                float alpha = exp2f(m_run[mi] - mnew);
                l_run[mi] = l_run[mi] * alpha + ls;
                m_run[mi] = mnew;
                #pragma unroll
                for (int df = 0; df < 8; df++)
                    #pragma unroll
                    for (int e = 0; e < 4; e++)
                        o_acc[mi][df][e] *= alpha;
            }
            // pack P to bf16 pairs: X*=ni0, Y*=ni1 (low halves = even kv)
            unsigned X0, X1, Y0, Y1;
            asm("v_cvt_pk_bf16_f32 %0, %1, %2" : "=v"(X0) : "v"(ps[0][0]), "v"(ps[0][1]));
            asm("v_cvt_pk_bf16_f32 %0, %1, %2" : "=v"(X1) : "v"(ps[0][2]), "v"(ps[0][3]));
            asm("v_cvt_pk_bf16_f32 %0, %1, %2" : "=v"(Y0) : "v"(ps[1][0]), "v"(ps[1][1]));
            asm("v_cvt_pk_bf16_f32 %0, %1, %2" : "=v"(Y1) : "v"(ps[1][2]), "v"(ps[1][3]));
            // redistribute across the 4 lane-groups: target lane (g,r16) needs
            // kv = g*8..g*8+7 for q=r16 -> pure g-space shuffle (r16 preserved).
            const int sle = ((lane & 16) << 1) | r16;   // src lane gs=2*(g&1)
            const int slo = sle + 16;                   // src lane gs=2*(g&1)+1
            int a0 = __shfl((int)X0, sle), b0 = __shfl((int)Y0, sle);
            int a1 = __shfl((int)X1, sle), b1 = __shfl((int)Y1, sle);
            int a2 = __shfl((int)X0, slo), b2 = __shfl((int)Y0, slo);
            int a3 = __shfl((int)X1, slo), b3 = __shfl((int)Y1, slo);
            bool hi = (lane >= 32);                     // g>=2 -> kv block ni=1
            int4 wv = make_int4(hi ? b0 : a0, hi ? b1 : a1,
                                hi ? b2 : a2, hi ? b3 : a3);
            pb[mi] = __builtin_bit_cast(short8, wv);
        }

        // ---- O^T += V^T P^T, V from LDS (swizzled reads) ----
        const int swv = ((g ^ (r16 & 3)) << 3);
        #pragma unroll
        for (int df = 0; df < 8; df++) {
            short8 vf = *reinterpret_cast<const short8*>(Vl + (df * 16 + r16) * 32 + swv);
            __builtin_amdgcn_s_setprio(1);
            o_acc[0][df] = __builtin_amdgcn_mfma_f32_16x16x32_bf16(vf, pb[0], o_acc[0][df], 0, 0, 0);
            o_acc[1][df] = __builtin_amdgcn_mfma_f32_16x16x32_bf16(vf, pb[1], o_acc[1][df], 0, 0, 0);
            __builtin_amdgcn_s_setprio(0);
        }

        __builtin_amdgcn_sched_barrier(0);
        __builtin_amdgcn_s_barrier();      // all waves done reading buf[cur]
        __builtin_amdgcn_sched_barrier(0);
        cur ^= 1;
    }

    // ---- epilogue ----
    if (direct) {
        #pragma unroll
        for (int mi = 0; mi < 2; mi++) {
            float inv = 1.0f / l_run[mi];
            #pragma unroll
            for (int df = 0; df < 8; df++) {
                f32x4 r = o_acc[mi][df];
                r[0] *= inv; r[1] *= inv; r[2] *= inv; r[3] *= inv;
                *reinterpret_cast<f32x4*>(
                    &O[(size_t)(qw + mi * 16 + r16) * DK + df * 16 + g * 4]) = r;
            }
        }
    } else {
        size_t pb0i = ((size_t)t * max_chunks + c) * 32;
        #pragma unroll
        for (int mi = 0; mi < 2; mi++) {
            int q = mi * 16 + r16;
            #pragma unroll
            for (int df = 0; df < 8; df++) {
                ushort4 h;
                h.x = f2bf(o_acc[mi][df][0]); h.y = f2bf(o_acc[mi][df][1]);
                h.z = f2bf(o_acc[mi][df][2]); h.w = f2bf(o_acc[mi][df][3]);
                *reinterpret_cast<ushort4*>(
                    &OpartH[(pb0i + q) * 128 + df * 16 + g * 4]) = h;
            }
            if (g == 0) { Mpart[pb0i + q] = m_run[mi]; Lpart[pb0i + q] = l_run[mi]; }
        }
    }
}

// ---------------- merge bf16 partials across chunks (exp2 domain) ----------------
__global__ __launch_bounds__(256) void attn_merge(
    const unsigned short* __restrict__ OpartH, const float* __restrict__ Mpart,
    const float* __restrict__ Lpart, float* __restrict__ O,
    int chunk_tiles, int max_chunks)
{
    __shared__ float Ms[32], Ls[32], Fs[32][32];
    const int t = blockIdx.x;
    const int nc = t / chunk_tiles + 1;
    const int tid = threadIdx.x;

    if (tid < 32) {
        float M = -1e30f;
        for (int c = 0; c < nc; c++)
            M = fmaxf(M, Mpart[((size_t)t * max_chunks + c) * 32 + tid]);
        float L = 0.f;
        for (int c = 0; c < nc; c++) {
            size_t pb = ((size_t)t * max_chunks + c) * 32 + tid;
            L += exp2f(Mpart[pb] - M) * Lpart[pb];
        }
        Ms[tid] = M; Ls[tid] = L;
    }
    __syncthreads();
    for (int cc = tid >> 5; cc < nc; cc += 8) {
        int row = tid & 31;
        Fs[cc][row] = exp2f(Mpart[((size_t)t * max_chunks + cc) * 32 + row] - Ms[row]);
    }
    __syncthreads();
    #pragma unroll
    for (int it = 0; it < 2; it++) {
        int idx = tid + it * 256;       // 512 = 32 rows x 16 col-groups of 8
        int row = idx >> 4, c8 = idx & 15;
        float accv[8] = {};
        for (int c = 0; c < nc; c++) {
            short8 u = *reinterpret_cast<const short8*>(
                &OpartH[(((size_t)t * max_chunks + c) * 32 + row) * 128 + c8 * 8]);
            float f = Fs[c][row];
            #pragma unroll
            for (int k = 0; k < 8; k++) {
                unsigned uv = ((unsigned)(unsigned short)u[k]) << 16;
                accv[k] += f * __builtin_bit_cast(float, uv);
            }
        }
        float inv = 1.0f / Ls[row];
        float* dst = &O[((size_t)t * 32 + row) * DK + c8 * 8];
        float4 r0 = {accv[0] * inv, accv[1] * inv, accv[2] * inv, accv[3] * inv};
        float4 r1 = {accv[4] * inv, accv[5] * inv, accv[6] * inv, accv[7] * inv};
        *reinterpret_cast<float4*>(dst) = r0;
        *reinterpret_cast<float4*>(dst + 4) = r1;
    }
}

extern "C" void kernel_launch(void* const* d_in, const int* in_sizes, int n_in,
                              void* d_out, int out_size, void* d_ws, size_t ws_size,
                              hipStream_t stream) {
    const float* X  = (const float*)d_in[0];
    const float* Wq = (const float*)d_in[1];
    const float* bq = (const float*)d_in[2];
    const float* Wk = (const float*)d_in[3];
    const float* bk = (const float*)d_in[4];
    const float* Wv = (const float*)d_in[5];
    const float* bv = (const float*)d_in[6];
    float* O = (float*)d_out;

    unsigned short* Qb = (unsigned short*)d_ws;
    unsigned short* Kb = Qb + (size_t)N_TOK * DK;
    unsigned short* Vt = Kb + (size_t)N_TOK * DK;
    unsigned short* Wt = Vt + (size_t)N_TOK * DK;
    float* Mbase = (float*)(Wt + (size_t)3 * DK * D_IN);
    size_t base_bytes = (size_t)((char*)Mbase - (char*)d_ws);

    // ladder: pick smallest chunk (most parallelism) whose partials fit ws
    int chunk_tiles = 0, max_chunks = 1, direct = 0;
    const int opts[5] = {8, 16, 32, 64, 128};
    for (int i = 0; i < 5; i++) {
        int ct = opts[i], mc = NT / ct;
        size_t need = base_bytes
                    + (size_t)NT * mc * 32 * 2 * sizeof(float)      // M, L
                    + (size_t)NT * mc * 32 * 128 * 2;               // Opart bf16
        if (need <= ws_size) { chunk_tiles = ct; max_chunks = mc; break; }
    }
    if (!chunk_tiles) { chunk_tiles = NT; max_chunks = 1; direct = 1; }
    float* Mpart = Mbase;
    float* Lpart = Mpart + (size_t)NT * max_chunks * 32;
    unsigned short* OpartH = (unsigned short*)(Lpart + (size_t)NT * max_chunks * 32);

    wtrans_kernel<<<dim3(32, 3), 256, 0, stream>>>(Wq, Wk, Wv, Wt);
    proj_fused<<<dim3(512), 256, 0, stream>>>(X, Wt, bq, bk, bv, Qb, Kb, Vt);
    int grid_c = direct ? 1 : max_chunks;
    attn_partial<<<dim3(64, grid_c), 256, 0, stream>>>(
        Qb, Kb, Vt, OpartH, Mpart, Lpart, O, chunk_tiles, max_chunks, direct);
    if (!direct)
        attn_merge<<<dim3(NT), 256, 0, stream>>>(OpartH, Mpart, Lpart, O,
                                                 chunk_tiles, max_chunks);
}

// Round 9
// 138.233 us; speedup vs baseline: 1.1524x; 1.1524x over previous
//
#include <hip/hip_runtime.h>
#include <hip/hip_bf16.h>

#define N_TOK 8192
#define D_IN  1024
#define DK    128
#define NT    256   // number of 32-row q tiles (== number of 32-row kv tiles)

typedef __attribute__((ext_vector_type(8))) short short8;
typedef __attribute__((ext_vector_type(4))) float f32x4;

static __device__ __forceinline__ unsigned short f2bf(float f) {
    __hip_bfloat16 h = __float2bfloat16(f);
    return __builtin_bit_cast(unsigned short, h);
}

static __device__ __forceinline__ void gl_lds16(const void* g, void* l) {
    __builtin_amdgcn_global_load_lds(
        (const __attribute__((address_space(1))) void*)g,
        (__attribute__((address_space(3))) void*)l, 16, 0, 0);
}

// ---------------- one-time W transpose: W[k][n] f32 -> Wt[n][k] bf16 ----------------
__global__ __launch_bounds__(256) void wtrans_kernel(
    const float* __restrict__ Wq, const float* __restrict__ Wk,
    const float* __restrict__ Wv, unsigned short* __restrict__ Wt)
{
    __shared__ unsigned short T[64][72];
    const int proj = blockIdx.y;
    const float* W = (proj == 0) ? Wq : (proj == 1) ? Wk : Wv;
    unsigned short* out = Wt + (size_t)proj * DK * D_IN;
    const int k0 = (blockIdx.x & 15) * 64, n0 = (blockIdx.x >> 4) * 64;
    const int tid = threadIdx.x;
    #pragma unroll
    for (int i = 0; i < 4; i++) {
        int e = tid + i * 256;
        int r = e >> 4, c4 = e & 15;
        float4 v = *reinterpret_cast<const float4*>(&W[(size_t)(k0 + r) * DK + n0 + c4 * 4]);
        T[c4 * 4 + 0][r] = f2bf(v.x);
        T[c4 * 4 + 1][r] = f2bf(v.y);
        T[c4 * 4 + 2][r] = f2bf(v.z);
        T[c4 * 4 + 3][r] = f2bf(v.w);
    }
    __syncthreads();
    #pragma unroll
    for (int i = 0; i < 4; i++) {
        int e = tid + i * 256;
        int r = e >> 4, c4 = e & 15;
        *reinterpret_cast<ushort4*>(&out[(size_t)(n0 + r) * D_IN + k0 + c4 * 4]) =
            *reinterpret_cast<const ushort4*>(&T[r][c4 * 4]);
    }
}

// ---------------- X f32 -> bf16 cast with 16B-block row swizzle ----------------
// Xb[m][b'] block b' = (b&~7) | ((b&7)^(m&7)) so proj can gl_lds linearly and
// ds_read conflict-free.
__global__ __launch_bounds__(256) void xcast_kernel(
    const float* __restrict__ X, unsigned short* __restrict__ Xb)
{
    const int idx = blockIdx.x * 256 + threadIdx.x;   // one 16B out block
    const int m = idx >> 7, b = idx & 127;
    const float* src = &X[(size_t)m * D_IN + b * 8];
    const float4 v0 = *reinterpret_cast<const float4*>(src);
    const float4 v1 = *reinterpret_cast<const float4*>(src + 4);
    short8 h;
    h[0] = f2bf(v0.x); h[1] = f2bf(v0.y); h[2] = f2bf(v0.z); h[3] = f2bf(v0.w);
    h[4] = f2bf(v1.x); h[5] = f2bf(v1.y); h[6] = f2bf(v1.z); h[7] = f2bf(v1.w);
    const int bp = (b & ~7) | ((b & 7) ^ (m & 7));
    *reinterpret_cast<short8*>(&Xb[(size_t)m * D_IN + bp * 8]) = h;
}

// ---------------- fused QKV projection: bf16 X via gl_lds, 512 blocks ----------
// BM=16; 4 waves split 384 cols (96 each). X staged via global_load_lds with
// counted vmcnt(1); W fragments straight from bf16 Wt (L2-resident).
// Q row-major PRE-SCALED by 1/sqrt(dk)*log2e; K 16B-block-swizzled; V trans+swz.
__global__ __launch_bounds__(256) void proj_fused(
    const unsigned short* __restrict__ Xb, const unsigned short* __restrict__ Wt,
    const float* __restrict__ bq, const float* __restrict__ bk,
    const float* __restrict__ bv,
    unsigned short* __restrict__ Qb, unsigned short* __restrict__ Kb,
    unsigned short* __restrict__ Vt)
{
    __shared__ unsigned short Xs[2][16][64];   // 2 x 2 KB

    const int tid = threadIdx.x;
    const int wid = tid >> 6, lane = tid & 63;
    const int g = lane >> 4, r16 = lane & 15;
    const int mb = blockIdx.x * 16;
    const float scale2 = 0.08838834764831845f * 1.4426950408889634f;

    auto STAGE_X = [&](int buf, int k0) {     // 2048 B: 128 threads x 16 B
        if (tid < 128) {
            int off = tid * 16;
            int d = tid >> 3, cb = off & 127;
            gl_lds16((const char*)Xb + (((size_t)(mb + d) * D_IN + k0) << 1) + cb,
                     (char*)&Xs[buf][0][0] + off);
        }
    };

    f32x4 acc[6] = {};   // wave cols [96*wid, 96*wid+96)

    STAGE_X(0, 0);
    for (int s = 0; s < 16; ++s) {
        const int k0 = s * 64;
        const int cur = s & 1;
        if (s + 1 < 16) {
            STAGE_X(cur ^ 1, k0 + 64);
            asm volatile("s_waitcnt vmcnt(1)" ::: "memory");
        } else {
            asm volatile("s_waitcnt vmcnt(0)" ::: "memory");
        }
        __builtin_amdgcn_sched_barrier(0);
        __builtin_amdgcn_s_barrier();
        __builtin_amdgcn_sched_barrier(0);

        #pragma unroll
        for (int kk = 0; kk < 64; kk += 32) {
            int blk = (kk >> 3) | g;
            short8 af = *reinterpret_cast<const short8*>(
                &Xs[cur][r16][((blk ^ (r16 & 7)) << 3)]);
            short8 bfr[6];
            #pragma unroll
            for (int ni = 0; ni < 6; ni++) {
                int nn = wid * 96 + ni * 16;
                int pj = nn >> 7;
                bfr[ni] = *reinterpret_cast<const short8*>(
                    &Wt[((size_t)pj * DK + (nn & 127) + r16) * D_IN + k0 + kk + g * 8]);
            }
            __builtin_amdgcn_s_setprio(1);
            #pragma unroll
            for (int ni = 0; ni < 6; ni++)
                acc[ni] = __builtin_amdgcn_mfma_f32_16x16x32_bf16(
                    af, bfr[ni], acc[ni], 0, 0, 0);
            __builtin_amdgcn_s_setprio(0);
        }
        __builtin_amdgcn_sched_barrier(0);
        __builtin_amdgcn_s_barrier();      // buf[cur^1] reads done before overwrite
        __builtin_amdgcn_sched_barrier(0);
    }

    // ---- epilogue ----
    #pragma unroll
    for (int ni = 0; ni < 6; ni++) {
        int nn = wid * 96 + ni * 16;
        int pj = nn >> 7;
        int n = (nn & 127) + r16;
        const float* bias = (pj == 0) ? bq : (pj == 1) ? bk : bv;
        float b = bias[n];
        if (pj < 2) {
            unsigned short* out = (pj == 0) ? Qb : Kb;
            #pragma unroll
            for (int e = 0; e < 4; e++) {
                int m = mb + g * 4 + e;
                float val = acc[ni][e] + b;
                int nc = n;
                if (pj == 1)   // K swizzle: 16B block ^= (kv&7)
                    nc = ((((n >> 3) ^ (m & 7)) << 3) | (n & 7));
                else
                    val *= scale2;         // fold softmax scale into Q
                out[(size_t)m * DK + nc] = f2bf(val);
            }
        } else {
            int m0 = mb + g * 4;
            // V swizzle within 64-kv group: block' = ((m>>3)&7) ^ (d&7)
            int mp = (m0 & ~63) | (((((m0 >> 3) & 7) ^ (n & 7))) << 3) | (m0 & 7);
            ushort4 h;
            h.x = f2bf(acc[ni][0] + b);
            h.y = f2bf(acc[ni][1] + b);
            h.z = f2bf(acc[ni][2] + b);
            h.w = f2bf(acc[ni][3] + b);
            *reinterpret_cast<ushort4*>(&Vt[(size_t)n * N_TOK + mp]) = h;
        }
    }
}

// ---------------- causal flash attention: KVBLK=64, in-register P, bf16 partials --
// grid = (64 q-blocks, max_chunks). Block (qb,c): q rows [qb*128,+128), kv tiles
// [c*ct, min((c+1)*ct, 4qb+4)) processed in PAIRS (64 kv per barrier interval).
// 4 waves of 32 q-rows share 64 KB LDS K/V (2 blocks/CU). Counted-vmcnt dbuf.
__global__ __launch_bounds__(256, 2) void attn_partial(
    const unsigned short* __restrict__ Qb, const unsigned short* __restrict__ Ksw,
    const unsigned short* __restrict__ Vsw,
    unsigned short* __restrict__ OpartH, float* __restrict__ Mpart,
    float* __restrict__ Lpart,
    float* __restrict__ O, int chunk_tiles, int max_chunks, int direct)
{
    __shared__ unsigned short Klds[2][64][128];   // 32 KB
    __shared__ unsigned short Vlds[2][128][64];   // 32 KB

    const int qb = blockIdx.x, c = blockIdx.y;
    const int j0 = c * chunk_tiles;               // ct multiple of 4 => j0-4qb ≡ 0 (4)
    const int jmax = 4 * qb + 4;                  // => first tile never fully masked
    const int jend = min(j0 + chunk_tiles, jmax);
    if (j0 >= jend) return;
    const int np = (jend - j0) >> 1;              // pairs (nt even: ct, jmax, j0 even)

    const int tid = threadIdx.x;
    const int wid = tid >> 6, lane = tid & 63;
    const int g = lane >> 4, r16 = lane & 15;
    const int t = qb * 4 + wid;     // this wave's 32-row q tile index
    const int qw = t * 32;

    auto STAGE = [&](int buf, int kvb) {   // 8 gl_lds per thread (K 16KB + V 16KB)
        #pragma unroll
        for (int s = 0; s < 4; s++) {
            int off = s * 4096 + tid * 16;
            gl_lds16((const char*)Ksw + ((size_t)kvb << 8) + off,
                     (char*)&Klds[buf][0][0] + off);
        }
        #pragma unroll
        for (int s = 0; s < 4; s++) {
            int off = s * 4096 + tid * 16;
            int d = off >> 7, cb = off & 127;
            gl_lds16((const char*)Vsw + (((size_t)d * N_TOK + kvb) << 1) + cb,
                     (char*)&Vlds[buf][0][0] + off);
        }
    };

    // Q fragments (B-operand): col=q=mi*16+r16, k=d  (Q pre-scaled)
    short8 qf[2][4];
    #pragma unroll
    for (int mi = 0; mi < 2; mi++)
        #pragma unroll
        for (int kd = 0; kd < 4; kd++)
            qf[mi][kd] = *reinterpret_cast<const short8*>(
                &Qb[(size_t)(qw + mi * 16 + r16) * DK + kd * 32 + g * 8]);

    f32x4 o_acc[2][8] = {};                  // O^T: [q-frag mi][d-frag df]
    float m_run[2] = {-1e30f, -1e30f}, l_run[2] = {0.f, 0.f};

    STAGE(0, j0 * 32);

    int cur = 0;
    for (int it = 0; it < np; ++it) {
        const int kvb = (j0 + it * 2) * 32;
        if (it + 1 < np) {
            STAGE(cur ^ 1, kvb + 64);
            asm volatile("s_waitcnt vmcnt(8)" ::: "memory");   // prev pair landed
        } else {
            asm volatile("s_waitcnt vmcnt(0)" ::: "memory");
        }
        __builtin_amdgcn_sched_barrier(0);
        __builtin_amdgcn_s_barrier();
        __builtin_amdgcn_sched_barrier(0);

        const unsigned short* Kl = &Klds[cur][0][0];
        const unsigned short* Vl = &Vlds[cur][0][0];

        // ---- S^T = K Q^T from LDS (swizzled reads), 64 kv x 32 q ----
        f32x4 st[4][2] = {};                 // [ni=kv frag][mi=q frag]
        #pragma unroll
        for (int kd = 0; kd < 4; kd++) {
            int swb = ((((kd << 2) | g) ^ (r16 & 7)) << 3);
            short8 kf[4];
            #pragma unroll
            for (int ni = 0; ni < 4; ni++)
                kf[ni] = *reinterpret_cast<const short8*>(
                    Kl + (ni * 16 + r16) * 128 + swb);
            __builtin_amdgcn_s_setprio(1);
            #pragma unroll
            for (int ni = 0; ni < 4; ni++)
                #pragma unroll
                for (int mi = 0; mi < 2; mi++)
                    st[ni][mi] = __builtin_amdgcn_mfma_f32_16x16x32_bf16(
                        kf[ni], qf[mi][kd], st[ni][mi], 0, 0, 0);
            __builtin_amdgcn_s_setprio(0);
        }

        // ---- online softmax (exp2 domain, scale pre-folded) + in-reg P pack ----
        const bool anymask = (kvb + 63 > qw);
        short8 pb[2][2];
        #pragma unroll
        for (int mi = 0; mi < 2; mi++) {
            const int qrow = qw + mi * 16 + r16;
            float sv[4][4];
            #pragma unroll
            for (int ni = 0; ni < 4; ni++)
                #pragma unroll
                for (int e = 0; e < 4; e++) {
                    float v = st[ni][mi][e];
                    if (anymask && (kvb + ni * 16 + g * 4 + e > qrow)) v = -1e30f;
                    sv[ni][e] = v;
                }
            float lm = fmaxf(
                fmaxf(fmaxf(fmaxf(sv[0][0], sv[0][1]), fmaxf(sv[0][2], sv[0][3])),
                      fmaxf(fmaxf(sv[1][0], sv[1][1]), fmaxf(sv[1][2], sv[1][3]))),
                fmaxf(fmaxf(fmaxf(sv[2][0], sv[2][1]), fmaxf(sv[2][2], sv[2][3])),
                      fmaxf(fmaxf(sv[3][0], sv[3][1]), fmaxf(sv[3][2], sv[3][3]))));
            lm = fmaxf(lm, __shfl_xor(lm, 16));
            lm = fmaxf(lm, __shfl_xor(lm, 32));
            // T13 defer-rescale (P bounded by 2^8; first tile never fully masked)
            bool nog = __all(lm - m_run[mi] <= 8.0f);
            float mnew = nog ? m_run[mi] : fmaxf(m_run[mi], lm);
            float ps[4][4];
            #pragma unroll
            for (int ni = 0; ni < 4; ni++)
                #pragma unroll
                for (int e = 0; e < 4; e++)
                    ps[ni][e] = exp2f(sv[ni][e] - mnew);
            float ls = (((ps[0][0] + ps[0][1]) + (ps[0][2] + ps[0][3]))
                     +  ((ps[1][0] + ps[1][1]) + (ps[1][2] + ps[1][3])))
                     + (((ps[2][0] + ps[2][1]) + (ps[2][2] + ps[2][3]))
                     +  ((ps[3][0] + ps[3][1]) + (ps[3][2] + ps[3][3])));
            ls += __shfl_xor(ls, 16);
            ls += __shfl_xor(ls, 32);
            if (nog) {
                l_run[mi] += ls;
            } else {
                float alpha = exp2f(m_run[mi] - mnew);
                l_run[mi] = l_run[mi] * alpha + ls;
                m_run[mi] = mnew;
                #pragma unroll
                for (int df = 0; df < 8; df++)
                    #pragma unroll
                    for (int e = 0; e < 4; e++)
                        o_acc[mi][df][e] *= alpha;
            }
            // pack P -> bf16 B-fragments, ks = kv 32-half
            const int sle = ((lane & 16) << 1) | r16;
            const int slo = sle + 16;
            const bool hi = (lane >= 32);
            #pragma unroll
            for (int ks = 0; ks < 2; ks++) {
                unsigned X0, X1, Y0, Y1;
                asm("v_cvt_pk_bf16_f32 %0, %1, %2" : "=v"(X0) : "v"(ps[2*ks][0]),   "v"(ps[2*ks][1]));
                asm("v_cvt_pk_bf16_f32 %0, %1, %2" : "=v"(X1) : "v"(ps[2*ks][2]),   "v"(ps[2*ks][3]));
                asm("v_cvt_pk_bf16_f32 %0, %1, %2" : "=v"(Y0) : "v"(ps[2*ks+1][0]), "v"(ps[2*ks+1][1]));
                asm("v_cvt_pk_bf16_f32 %0, %1, %2" : "=v"(Y1) : "v"(ps[2*ks+1][2]), "v"(ps[2*ks+1][3]));
                int a0 = __shfl((int)X0, sle), b0 = __shfl((int)Y0, sle);
                int a1 = __shfl((int)X1, sle), b1 = __shfl((int)Y1, sle);
                int a2 = __shfl((int)X0, slo), b2 = __shfl((int)Y0, slo);
                int a3 = __shfl((int)X1, slo), b3 = __shfl((int)Y1, slo);
                int4 wv = make_int4(hi ? b0 : a0, hi ? b1 : a1,
                                    hi ? b2 : a2, hi ? b3 : a3);
                pb[mi][ks] = __builtin_bit_cast(short8, wv);
            }
        }

        // ---- O^T += V^T P^T, V from LDS (swizzled reads) ----
        #pragma unroll
        for (int ks = 0; ks < 2; ks++) {
            __builtin_amdgcn_s_setprio(1);
            #pragma unroll
            for (int df = 0; df < 8; df++) {
                short8 vf = *reinterpret_cast<const short8*>(
                    Vl + (df * 16 + r16) * 64 + ((((ks << 2) | g) ^ (r16 & 7)) << 3));
                o_acc[0][df] = __builtin_amdgcn_mfma_f32_16x16x32_bf16(vf, pb[0][ks], o_acc[0][df], 0, 0, 0);
                o_acc[1][df] = __builtin_amdgcn_mfma_f32_16x16x32_bf16(vf, pb[1][ks], o_acc[1][df], 0, 0, 0);
            }
            __builtin_amdgcn_s_setprio(0);
        }

        __builtin_amdgcn_sched_barrier(0);
        __builtin_amdgcn_s_barrier();      // all waves done reading buf[cur]
        __builtin_amdgcn_sched_barrier(0);
        cur ^= 1;
    }

    // ---- epilogue ----
    if (direct) {
        #pragma unroll
        for (int mi = 0; mi < 2; mi++) {
            float inv = 1.0f / l_run[mi];
            #pragma unroll
            for (int df = 0; df < 8; df++) {
                f32x4 r = o_acc[mi][df];
                r[0] *= inv; r[1] *= inv; r[2] *= inv; r[3] *= inv;
                *reinterpret_cast<f32x4*>(
                    &O[(size_t)(qw + mi * 16 + r16) * DK + df * 16 + g * 4]) = r;
            }
        }
    } else {
        size_t pb0i = ((size_t)t * max_chunks + c) * 32;
        #pragma unroll
        for (int mi = 0; mi < 2; mi++) {
            int q = mi * 16 + r16;
            #pragma unroll
            for (int df = 0; df < 8; df++) {
                ushort4 h;
                h.x = f2bf(o_acc[mi][df][0]); h.y = f2bf(o_acc[mi][df][1]);
                h.z = f2bf(o_acc[mi][df][2]); h.w = f2bf(o_acc[mi][df][3]);
                *reinterpret_cast<ushort4*>(
                    &OpartH[(pb0i + q) * 128 + df * 16 + g * 4]) = h;
            }
            if (g == 0) { Mpart[pb0i + q] = m_run[mi]; Lpart[pb0i + q] = l_run[mi]; }
        }
    }
}

// ---------------- merge bf16 partials across chunks (exp2 domain) ----------------
__global__ __launch_bounds__(256) void attn_merge(
    const unsigned short* __restrict__ OpartH, const float* __restrict__ Mpart,
    const float* __restrict__ Lpart, float* __restrict__ O,
    int chunk_tiles, int max_chunks)
{
    __shared__ float Ms[32], Ls[32], Fs[16][32];
    const int t = blockIdx.x;
    const int nc = t / chunk_tiles + 1;
    const int tid = threadIdx.x;

    if (tid < 32) {
        float M = -1e30f;
        for (int c = 0; c < nc; c++)
            M = fmaxf(M, Mpart[((size_t)t * max_chunks + c) * 32 + tid]);
        float L = 0.f;
        for (int c = 0; c < nc; c++) {
            size_t pb = ((size_t)t * max_chunks + c) * 32 + tid;
            L += exp2f(Mpart[pb] - M) * Lpart[pb];
        }
        Ms[tid] = M; Ls[tid] = L;
    }
    __syncthreads();
    for (int cc = tid >> 5; cc < nc; cc += 8) {
        int row = tid & 31;
        Fs[cc][row] = exp2f(Mpart[((size_t)t * max_chunks + cc) * 32 + row] - Ms[row]);
    }
    __syncthreads();
    #pragma unroll
    for (int it = 0; it < 2; it++) {
        int idx = tid + it * 256;       // 512 = 32 rows x 16 col-groups of 8
        int row = idx >> 4, c8 = idx & 15;
        float accv[8] = {};
        for (int c = 0; c < nc; c++) {
            short8 u = *reinterpret_cast<const short8*>(
                &OpartH[(((size_t)t * max_chunks + c) * 32 + row) * 128 + c8 * 8]);
            float f = Fs[c][row];
            #pragma unroll
            for (int k = 0; k < 8; k++) {
                unsigned uv = ((unsigned)(unsigned short)u[k]) << 16;
                accv[k] += f * __builtin_bit_cast(float, uv);
            }
        }
        float inv = 1.0f / Ls[row];
        float* dst = &O[((size_t)t * 32 + row) * DK + c8 * 8];
        float4 r0 = {accv[0] * inv, accv[1] * inv, accv[2] * inv, accv[3] * inv};
        float4 r1 = {accv[4] * inv, accv[5] * inv, accv[6] * inv, accv[7] * inv};
        *reinterpret_cast<float4*>(dst) = r0;
        *reinterpret_cast<float4*>(dst + 4) = r1;
    }
}

extern "C" void kernel_launch(void* const* d_in, const int* in_sizes, int n_in,
                              void* d_out, int out_size, void* d_ws, size_t ws_size,
                              hipStream_t stream) {
    const float* X  = (const float*)d_in[0];
    const float* Wq = (const float*)d_in[1];
    const float* bq = (const float*)d_in[2];
    const float* Wk = (const float*)d_in[3];
    const float* bk = (const float*)d_in[4];
    const float* Wv = (const float*)d_in[5];
    const float* bv = (const float*)d_in[6];
    float* O = (float*)d_out;

    unsigned short* Qb = (unsigned short*)d_ws;
    unsigned short* Kb = Qb + (size_t)N_TOK * DK;
    unsigned short* Vt = Kb + (size_t)N_TOK * DK;
    unsigned short* Wt = Vt + (size_t)N_TOK * DK;
    unsigned short* Xb = Wt + (size_t)3 * DK * D_IN;
    float* Mbase = (float*)(Xb + (size_t)N_TOK * D_IN);
    size_t base_bytes = (size_t)((char*)Mbase - (char*)d_ws);

    // ladder: pick smallest chunk whose partials fit ws (ct must be mult of 4)
    int chunk_tiles = 0, max_chunks = 1, direct = 0;
    const int opts[4] = {16, 32, 64, 128};
    for (int i = 0; i < 4; i++) {
        int ct = opts[i], mc = NT / ct;
        size_t need = base_bytes
                    + (size_t)NT * mc * 32 * 2 * sizeof(float)      // M, L
                    + (size_t)NT * mc * 32 * 128 * 2;               // Opart bf16
        if (need <= ws_size) { chunk_tiles = ct; max_chunks = mc; break; }
    }
    if (!chunk_tiles) { chunk_tiles = NT; max_chunks = 1; direct = 1; }
    float* Mpart = Mbase;
    float* Lpart = Mpart + (size_t)NT * max_chunks * 32;
    unsigned short* OpartH = (unsigned short*)(Lpart + (size_t)NT * max_chunks * 32);

    wtrans_kernel<<<dim3(32, 3), 256, 0, stream>>>(Wq, Wk, Wv, Wt);
    xcast_kernel<<<dim3(4096), 256, 0, stream>>>(X, Xb);
    proj_fused<<<dim3(512), 256, 0, stream>>>(Xb, Wt, bq, bk, bv, Qb, Kb, Vt);
    int grid_c = direct ? 1 : max_chunks;
    attn_partial<<<dim3(64, grid_c), 256, 0, stream>>>(
        Qb, Kb, Vt, OpartH, Mpart, Lpart, O, chunk_tiles, max_chunks, direct);
    if (!direct)
        attn_merge<<<dim3(NT), 256, 0, stream>>>(OpartH, Mpart, Lpart, O,
                                                 chunk_tiles, max_chunks);
}

// Round 10
// 126.924 us; speedup vs baseline: 1.2551x; 1.0891x over previous
//
#include <hip/hip_runtime.h>
#include <hip/hip_bf16.h>

#define N_TOK 8192
#define D_IN  1024
#define DK    128
#define NT    256   // number of 32-row q tiles (== number of 32-row kv tiles)

typedef __attribute__((ext_vector_type(8))) short short8;
typedef __attribute__((ext_vector_type(4))) float f32x4;

static __device__ __forceinline__ unsigned short f2bf(float f) {
    __hip_bfloat16 h = __float2bfloat16(f);
    return __builtin_bit_cast(unsigned short, h);
}

static __device__ __forceinline__ void gl_lds16(const void* g, void* l) {
    __builtin_amdgcn_global_load_lds(
        (const __attribute__((address_space(1))) void*)g,
        (__attribute__((address_space(3))) void*)l, 16, 0, 0);
}

// ---------------- one-time W transpose: W[k][n] f32 -> Wt[n][k] bf16 ----------------
__global__ __launch_bounds__(256) void wtrans_kernel(
    const float* __restrict__ Wq, const float* __restrict__ Wk,
    const float* __restrict__ Wv, unsigned short* __restrict__ Wt)
{
    __shared__ unsigned short T[64][72];
    const int proj = blockIdx.y;
    const float* W = (proj == 0) ? Wq : (proj == 1) ? Wk : Wv;
    unsigned short* out = Wt + (size_t)proj * DK * D_IN;
    const int k0 = (blockIdx.x & 15) * 64, n0 = (blockIdx.x >> 4) * 64;
    const int tid = threadIdx.x;
    #pragma unroll
    for (int i = 0; i < 4; i++) {
        int e = tid + i * 256;
        int r = e >> 4, c4 = e & 15;
        float4 v = *reinterpret_cast<const float4*>(&W[(size_t)(k0 + r) * DK + n0 + c4 * 4]);
        T[c4 * 4 + 0][r] = f2bf(v.x);
        T[c4 * 4 + 1][r] = f2bf(v.y);
        T[c4 * 4 + 2][r] = f2bf(v.z);
        T[c4 * 4 + 3][r] = f2bf(v.w);
    }
    __syncthreads();
    #pragma unroll
    for (int i = 0; i < 4; i++) {
        int e = tid + i * 256;
        int r = e >> 4, c4 = e & 15;
        *reinterpret_cast<ushort4*>(&out[(size_t)(n0 + r) * D_IN + k0 + c4 * 4]) =
            *reinterpret_cast<const ushort4*>(&T[r][c4 * 4]);
    }
}

// ---------------- X f32 -> bf16 cast with 16B-block row swizzle ----------------
// Xb[m][b'] with b' = (b&~7) | ((b&7)^(m&7)) so proj stages linearly via
// global_load_lds and ds_reads are conflict-free.
__global__ __launch_bounds__(256) void xcast_kernel(
    const float* __restrict__ X, unsigned short* __restrict__ Xb)
{
    const int idx = blockIdx.x * 256 + threadIdx.x;   // one 16B out block
    const int m = idx >> 7, b = idx & 127;
    const float* src = &X[(size_t)m * D_IN + b * 8];
    const float4 v0 = *reinterpret_cast<const float4*>(src);
    const float4 v1 = *reinterpret_cast<const float4*>(src + 4);
    short8 h;
    h[0] = f2bf(v0.x); h[1] = f2bf(v0.y); h[2] = f2bf(v0.z); h[3] = f2bf(v0.w);
    h[4] = f2bf(v1.x); h[5] = f2bf(v1.y); h[6] = f2bf(v1.z); h[7] = f2bf(v1.w);
    const int bp = (b & ~7) | ((b & 7) ^ (m & 7));
    *reinterpret_cast<short8*>(&Xb[(size_t)m * D_IN + bp * 8]) = h;
}

// ---------------- fused QKV projection: W stationary in registers ----------------
// grid = 768 blocks = 128 row-blocks(64 rows) x 6 col-groups(64 cols), XCD-
// clustered so the 6 col-group blocks of one row-block share an XCD (X slice
// L2-resident). Each wave holds its 16 cols' FULL W as 32 B-frags (128 VGPR,
// loaded once). X staged via global_load_lds, counted vmcnt, k-loop unrolled.
__global__ __launch_bounds__(256, 2) void proj_fused(
    const unsigned short* __restrict__ Xb, const unsigned short* __restrict__ Wt,
    const float* __restrict__ bq, const float* __restrict__ bk,
    const float* __restrict__ bv,
    unsigned short* __restrict__ Qb, unsigned short* __restrict__ Kb,
    unsigned short* __restrict__ Vt)
{
    __shared__ unsigned short Xs[2][64][64];   // 2 x 8 KB

    // bid -> (rb, cg) with all 6 cg of one rb on the same XCD (bid % 8)
    const int bid = blockIdx.x;
    const int t2 = bid >> 3;
    const int rb = (t2 / 6) * 8 + (bid & 7);   // 0..127
    const int cg = t2 % 6;                     // 0..5

    const int tid = threadIdx.x;
    const int wid = tid >> 6, lane = tid & 63;
    const int g = lane >> 4, r16 = lane & 15;
    const int mb = rb * 64;
    const int colv = cg * 64 + wid * 16 + r16;   // global output col 0..383
    const int pj = colv >> 7;
    const int n  = colv & 127;
    const float scale2 = 0.08838834764831845f * 1.4426950408889634f;

    // ---- W -> registers (once): 32 k-frags for this lane's column ----
    short8 wf[32];
    #pragma unroll
    for (int kd = 0; kd < 32; kd++)
        wf[kd] = *reinterpret_cast<const short8*>(
            &Wt[((size_t)pj * DK + n) * D_IN + kd * 32 + g * 8]);

    f32x4 acc[4] = {};   // 64 rows = 4 x 16-row frags, 16 cols

    auto STAGE_X = [&](int buf, int s) {       // 8 KB = 2 x 16B per thread
        #pragma unroll
        for (int i = 0; i < 2; i++) {
            int off = i * 4096 + tid * 16;
            int r = off >> 7, cb = off & 127;
            gl_lds16((const char*)Xb + (((size_t)(mb + r) * D_IN + s * 64) << 1) + cb,
                     (char*)&Xs[buf][0][0] + off);
        }
    };

    STAGE_X(0, 0);
    #pragma unroll
    for (int s = 0; s < 16; ++s) {
        const int cur = s & 1;
        if (s + 1 < 16) {
            STAGE_X(cur ^ 1, s + 1);
            asm volatile("s_waitcnt vmcnt(2)" ::: "memory");
        } else {
            asm volatile("s_waitcnt vmcnt(0)" ::: "memory");
        }
        __builtin_amdgcn_sched_barrier(0);
        __builtin_amdgcn_s_barrier();
        __builtin_amdgcn_sched_barrier(0);

        #pragma unroll
        for (int kk = 0; kk < 2; kk++) {
            short8 af[4];
            #pragma unroll
            for (int mi = 0; mi < 4; mi++) {
                int blk = ((kk << 2) | g) ^ (r16 & 7);
                af[mi] = *reinterpret_cast<const short8*>(
                    &Xs[cur][mi * 16 + r16][blk * 8]);
            }
            __builtin_amdgcn_s_setprio(1);
            #pragma unroll
            for (int mi = 0; mi < 4; mi++)
                acc[mi] = __builtin_amdgcn_mfma_f32_16x16x32_bf16(
                    af[mi], wf[2 * s + kk], acc[mi], 0, 0, 0);
            __builtin_amdgcn_s_setprio(0);
        }
        __builtin_amdgcn_sched_barrier(0);
        __builtin_amdgcn_s_barrier();
        __builtin_amdgcn_sched_barrier(0);
    }

    // ---- epilogue: bias, Q pre-scale, K/V swizzled layouts ----
    const float* bias = (pj == 0) ? bq : (pj == 1) ? bk : bv;
    float b = bias[n];
    #pragma unroll
    for (int mi = 0; mi < 4; mi++) {
        if (pj < 2) {
            unsigned short* out = (pj == 0) ? Qb : Kb;
            #pragma unroll
            for (int e = 0; e < 4; e++) {
                int m = mb + mi * 16 + g * 4 + e;
                float val = acc[mi][e] + b;
                int nc = n;
                if (pj == 1)   // K swizzle: 16B block ^= (kv&7)
                    nc = ((((n >> 3) ^ (m & 7)) << 3) | (n & 7));
                else
                    val *= scale2;           // fold softmax scale into Q
                out[(size_t)m * DK + nc] = f2bf(val);
            }
        } else {
            int m0 = mb + mi * 16 + g * 4;
            // V swizzle within 32-kv group: block' = ((m&31)>>3) ^ (d&3)
            int mblk = (((m0 & 31) >> 3) ^ (n & 3));
            int mp = (m0 & ~31) | (mblk << 3) | (m0 & 7);
            ushort4 h;
            h.x = f2bf(acc[mi][0] + b);
            h.y = f2bf(acc[mi][1] + b);
            h.z = f2bf(acc[mi][2] + b);
            h.w = f2bf(acc[mi][3] + b);
            *reinterpret_cast<ushort4*>(&Vt[(size_t)n * N_TOK + mp]) = h;
        }
    }
}

// ---------------- causal flash attention: 2-wave blocks for supply ----------------
// grid = (128 q-blocks, max_chunks), 128 threads. Block (qb,c): q rows
// [qb*64,+64), kv tiles [c*ct, min((c+1)*ct, 2qb+2)). 2 waves of 32 q-rows
// share 32 KB LDS K/V (5 blocks/CU cap). In-register P (cvt_pk + shfl),
// defer-rescale, Q pre-scaled, counted-vmcnt double buffer. qb reversed so
// long blocks dispatch first.
__global__ __launch_bounds__(128, 3) void attn_partial(
    const unsigned short* __restrict__ Qb, const unsigned short* __restrict__ Ksw,
    const unsigned short* __restrict__ Vsw,
    unsigned short* __restrict__ OpartH, float* __restrict__ Mpart,
    float* __restrict__ Lpart,
    float* __restrict__ O, int chunk_tiles, int max_chunks, int direct)
{
    __shared__ unsigned short Klds[2][32][128];   // 16 KB
    __shared__ unsigned short Vlds[2][128][32];   // 16 KB

    const int qb = 127 - (int)blockIdx.x;   // longest work first
    const int c = blockIdx.y;
    const int j0 = c * chunk_tiles;
    const int jmax = 2 * qb + 2;
    const int jend = min(j0 + chunk_tiles, jmax);
    if (j0 >= jend) return;
    const int nt = jend - j0;

    const int tid = threadIdx.x;
    const int wid = tid >> 6, lane = tid & 63;
    const int g = lane >> 4, r16 = lane & 15;
    const int t = qb * 2 + wid;     // this wave's 32-row q tile index
    const int qw = t * 32;
    // note: j0 multiple of 16, fully-masked first tile needs j0*32 > qw+31
    // i.e. j0 >= 2qb+wid+1; launch guarantees j0 <= 2qb+1 and j0 even => safe.

    auto STAGE = [&](int buf, int kvb) {   // 8 gl_lds per thread (K 8KB + V 8KB)
        #pragma unroll
        for (int s = 0; s < 4; s++) {
            int off = s * 2048 + tid * 16;
            gl_lds16((const char*)Ksw + ((size_t)kvb << 8) + off,
                     (char*)&Klds[buf][0][0] + off);
        }
        #pragma unroll
        for (int s = 0; s < 4; s++) {
            int off = s * 2048 + tid * 16;
            int d = off >> 6, cb = off & 63;
            gl_lds16((const char*)Vsw + (((size_t)d * N_TOK + kvb) << 1) + cb,
                     (char*)&Vlds[buf][0][0] + off);
        }
    };

    // Q fragments (B-operand): col=q=mi*16+r16, k=d  (Q pre-scaled)
    short8 qf[2][4];
    #pragma unroll
    for (int mi = 0; mi < 2; mi++)
        #pragma unroll
        for (int kd = 0; kd < 4; kd++)
            qf[mi][kd] = *reinterpret_cast<const short8*>(
                &Qb[(size_t)(qw + mi * 16 + r16) * DK + kd * 32 + g * 8]);

    f32x4 o_acc[2][8] = {};                  // O^T: [q-frag mi][d-frag df]
    float m_run[2] = {-1e30f, -1e30f}, l_run[2] = {0.f, 0.f};

    STAGE(0, j0 * 32);

    int cur = 0;
    for (int it = 0; it < nt; ++it) {
        const int kvb = (j0 + it) * 32;
        if (it + 1 < nt) {
            STAGE(cur ^ 1, kvb + 32);
            asm volatile("s_waitcnt vmcnt(8)" ::: "memory");   // tile it landed
        } else {
            asm volatile("s_waitcnt vmcnt(0)" ::: "memory");
        }
        __builtin_amdgcn_sched_barrier(0);
        __builtin_amdgcn_s_barrier();
        __builtin_amdgcn_sched_barrier(0);

        const unsigned short* Kl = &Klds[cur][0][0];
        const unsigned short* Vl = &Vlds[cur][0][0];

        // ---- S^T = K Q^T from LDS (swizzled reads) ----
        f32x4 st[2][2] = {};                 // [ni=kv frag][mi=q frag]
        #pragma unroll
        for (int kd = 0; kd < 4; kd++) {
            int swb = ((((kd << 2) | g) ^ (r16 & 7)) << 3);
            short8 kf0 = *reinterpret_cast<const short8*>(Kl + r16 * 128 + swb);
            short8 kf1 = *reinterpret_cast<const short8*>(Kl + (16 + r16) * 128 + swb);
            __builtin_amdgcn_s_setprio(1);
            st[0][0] = __builtin_amdgcn_mfma_f32_16x16x32_bf16(kf0, qf[0][kd], st[0][0], 0, 0, 0);
            st[0][1] = __builtin_amdgcn_mfma_f32_16x16x32_bf16(kf0, qf[1][kd], st[0][1], 0, 0, 0);
            st[1][0] = __builtin_amdgcn_mfma_f32_16x16x32_bf16(kf1, qf[0][kd], st[1][0], 0, 0, 0);
            st[1][1] = __builtin_amdgcn_mfma_f32_16x16x32_bf16(kf1, qf[1][kd], st[1][1], 0, 0, 0);
            __builtin_amdgcn_s_setprio(0);
        }

        // ---- online softmax (exp2 domain) + in-register P pack ----
        const bool anymask = (kvb + 31 > qw);
        short8 pb[2];
        #pragma unroll
        for (int mi = 0; mi < 2; mi++) {
            const int qrow = qw + mi * 16 + r16;
            float s[2][4];
            #pragma unroll
            for (int ni = 0; ni < 2; ni++)
                #pragma unroll
                for (int e = 0; e < 4; e++) {
                    float v = st[ni][mi][e];
                    if (anymask && (kvb + ni * 16 + g * 4 + e > qrow)) v = -1e30f;
                    s[ni][e] = v;
                }
            float lm = fmaxf(fmaxf(fmaxf(s[0][0], s[0][1]), fmaxf(s[0][2], s[0][3])),
                             fmaxf(fmaxf(s[1][0], s[1][1]), fmaxf(s[1][2], s[1][3])));
            lm = fmaxf(lm, __shfl_xor(lm, 16));
            lm = fmaxf(lm, __shfl_xor(lm, 32));
            // T13 defer-rescale: keep old max while growth <= 8 (P bounded 2^8)
            bool nog = __all(lm - m_run[mi] <= 8.0f);
            float mnew = nog ? m_run[mi] : fmaxf(m_run[mi], lm);
            float ps[2][4];
            #pragma unroll
            for (int ni = 0; ni < 2; ni++)
                #pragma unroll
                for (int e = 0; e < 4; e++)
                    ps[ni][e] = exp2f(s[ni][e] - mnew);
            float ls = ((ps[0][0] + ps[0][1]) + (ps[0][2] + ps[0][3]))
                     + ((ps[1][0] + ps[1][1]) + (ps[1][2] + ps[1][3]));
            ls += __shfl_xor(ls, 16);
            ls += __shfl_xor(ls, 32);
            if (nog) {
                l_run[mi] += ls;
            } else {
                float alpha = exp2f(m_run[mi] - mnew);
                l_run[mi] = l_run[mi] * alpha + ls;
                m_run[mi] = mnew;
                #pragma unroll
                for (int df = 0; df < 8; df++)
                    #pragma unroll
                    for (int e = 0; e < 4; e++)
                        o_acc[mi][df][e] *= alpha;
            }
            // pack P to bf16 pairs and redistribute across lane-groups in-reg
            unsigned X0, X1, Y0, Y1;
            asm("v_cvt_pk_bf16_f32 %0, %1, %2" : "=v"(X0) : "v"(ps[0][0]), "v"(ps[0][1]));
            asm("v_cvt_pk_bf16_f32 %0, %1, %2" : "=v"(X1) : "v"(ps[0][2]), "v"(ps[0][3]));
            asm("v_cvt_pk_bf16_f32 %0, %1, %2" : "=v"(Y0) : "v"(ps[1][0]), "v"(ps[1][1]));
            asm("v_cvt_pk_bf16_f32 %0, %1, %2" : "=v"(Y1) : "v"(ps[1][2]), "v"(ps[1][3]));
            const int sle = ((lane & 16) << 1) | r16;   // src lane gs=2*(g&1)
            const int slo = sle + 16;                   // src lane gs=2*(g&1)+1
            int a0 = __shfl((int)X0, sle), b0 = __shfl((int)Y0, sle);
            int a1 = __shfl((int)X1, sle), b1 = __shfl((int)Y1, sle);
            int a2 = __shfl((int)X0, slo), b2 = __shfl((int)Y0, slo);
            int a3 = __shfl((int)X1, slo), b3 = __shfl((int)Y1, slo);
            bool hi = (lane >= 32);                     // g>=2 -> kv block ni=1
            int4 wv = make_int4(hi ? b0 : a0, hi ? b1 : a1,
                                hi ? b2 : a2, hi ? b3 : a3);
            pb[mi] = __builtin_bit_cast(short8, wv);
        }

        // ---- O^T += V^T P^T, V from LDS (swizzled reads) ----
        const int swv = ((g ^ (r16 & 3)) << 3);
        #pragma unroll
        for (int df = 0; df < 8; df++) {
            short8 vf = *reinterpret_cast<const short8*>(Vl + (df * 16 + r16) * 32 + swv);
            __builtin_amdgcn_s_setprio(1);
            o_acc[0][df] = __builtin_amdgcn_mfma_f32_16x16x32_bf16(vf, pb[0], o_acc[0][df], 0, 0, 0);
            o_acc[1][df] = __builtin_amdgcn_mfma_f32_16x16x32_bf16(vf, pb[1], o_acc[1][df], 0, 0, 0);
            __builtin_amdgcn_s_setprio(0);
        }

        __builtin_amdgcn_sched_barrier(0);
        __builtin_amdgcn_s_barrier();      // all waves done reading buf[cur]
        __builtin_amdgcn_sched_barrier(0);
        cur ^= 1;
    }

    // ---- epilogue ----
    if (direct) {
        #pragma unroll
        for (int mi = 0; mi < 2; mi++) {
            float inv = 1.0f / l_run[mi];
            #pragma unroll
            for (int df = 0; df < 8; df++) {
                f32x4 r = o_acc[mi][df];
                r[0] *= inv; r[1] *= inv; r[2] *= inv; r[3] *= inv;
                *reinterpret_cast<f32x4*>(
                    &O[(size_t)(qw + mi * 16 + r16) * DK + df * 16 + g * 4]) = r;
            }
        }
    } else {
        size_t pb0i = ((size_t)t * max_chunks + c) * 32;
        #pragma unroll
        for (int mi = 0; mi < 2; mi++) {
            int q = mi * 16 + r16;
            #pragma unroll
            for (int df = 0; df < 8; df++) {
                ushort4 h;
                h.x = f2bf(o_acc[mi][df][0]); h.y = f2bf(o_acc[mi][df][1]);
                h.z = f2bf(o_acc[mi][df][2]); h.w = f2bf(o_acc[mi][df][3]);
                *reinterpret_cast<ushort4*>(
                    &OpartH[(pb0i + q) * 128 + df * 16 + g * 4]) = h;
            }
            if (g == 0) { Mpart[pb0i + q] = m_run[mi]; Lpart[pb0i + q] = l_run[mi]; }
        }
    }
}

// ---------------- merge bf16 partials across chunks (exp2 domain) ----------------
__global__ __launch_bounds__(256) void attn_merge(
    const unsigned short* __restrict__ OpartH, const float* __restrict__ Mpart,
    const float* __restrict__ Lpart, float* __restrict__ O,
    int chunk_tiles, int max_chunks)
{
    __shared__ float Ms[32], Ls[32], Fs[16][32];
    const int t = blockIdx.x;
    const int nc = t / chunk_tiles + 1;
    const int tid = threadIdx.x;

    if (tid < 32) {
        float M = -1e30f;
        for (int c = 0; c < nc; c++)
            M = fmaxf(M, Mpart[((size_t)t * max_chunks + c) * 32 + tid]);
        float L = 0.f;
        for (int c = 0; c < nc; c++) {
            size_t pb = ((size_t)t * max_chunks + c) * 32 + tid;
            L += exp2f(Mpart[pb] - M) * Lpart[pb];
        }
        Ms[tid] = M; Ls[tid] = L;
    }
    __syncthreads();
    for (int cc = tid >> 5; cc < nc; cc += 8) {
        int row = tid & 31;
        Fs[cc][row] = exp2f(Mpart[((size_t)t * max_chunks + cc) * 32 + row] - Ms[row]);
    }
    __syncthreads();
    #pragma unroll
    for (int it = 0; it < 2; it++) {
        int idx = tid + it * 256;       // 512 = 32 rows x 16 col-groups of 8
        int row = idx >> 4, c8 = idx & 15;
        float accv[8] = {};
        for (int c = 0; c < nc; c++) {
            short8 u = *reinterpret_cast<const short8*>(
                &OpartH[(((size_t)t * max_chunks + c) * 32 + row) * 128 + c8 * 8]);
            float f = Fs[c][row];
            #pragma unroll
            for (int k = 0; k < 8; k++) {
                unsigned uv = ((unsigned)(unsigned short)u[k]) << 16;
                accv[k] += f * __builtin_bit_cast(float, uv);
            }
        }
        float inv = 1.0f / Ls[row];
        float* dst = &O[((size_t)t * 32 + row) * DK + c8 * 8];
        float4 r0 = {accv[0] * inv, accv[1] * inv, accv[2] * inv, accv[3] * inv};
        float4 r1 = {accv[4] * inv, accv[5] * inv, accv[6] * inv, accv[7] * inv};
        *reinterpret_cast<float4*>(dst) = r0;
        *reinterpret_cast<float4*>(dst + 4) = r1;
    }
}

extern "C" void kernel_launch(void* const* d_in, const int* in_sizes, int n_in,
                              void* d_out, int out_size, void* d_ws, size_t ws_size,
                              hipStream_t stream) {
    const float* X  = (const float*)d_in[0];
    const float* Wq = (const float*)d_in[1];
    const float* bq = (const float*)d_in[2];
    const float* Wk = (const float*)d_in[3];
    const float* bk = (const float*)d_in[4];
    const float* Wv = (const float*)d_in[5];
    const float* bv = (const float*)d_in[6];
    float* O = (float*)d_out;

    unsigned short* Qb = (unsigned short*)d_ws;
    unsigned short* Kb = Qb + (size_t)N_TOK * DK;
    unsigned short* Vt = Kb + (size_t)N_TOK * DK;
    unsigned short* Wt = Vt + (size_t)N_TOK * DK;
    unsigned short* Xb = Wt + (size_t)3 * DK * D_IN;
    float* Mbase = (float*)(Xb + (size_t)N_TOK * D_IN);
    size_t base_bytes = (size_t)((char*)Mbase - (char*)d_ws);

    // ladder: pick smallest chunk whose partials fit ws (ct multiple of 16)
    int chunk_tiles = 0, max_chunks = 1, direct = 0;
    const int opts[4] = {16, 32, 64, 128};
    for (int i = 0; i < 4; i++) {
        int ct = opts[i], mc = NT / ct;
        size_t need = base_bytes
                    + (size_t)NT * mc * 32 * 2 * sizeof(float)      // M, L
                    + (size_t)NT * mc * 32 * 128 * 2;               // Opart bf16
        if (need <= ws_size) { chunk_tiles = ct; max_chunks = mc; break; }
    }
    if (!chunk_tiles) { chunk_tiles = NT; max_chunks = 1; direct = 1; }
    float* Mpart = Mbase;
    float* Lpart = Mpart + (size_t)NT * max_chunks * 32;
    unsigned short* OpartH = (unsigned short*)(Lpart + (size_t)NT * max_chunks * 32);

    wtrans_kernel<<<dim3(32, 3), 256, 0, stream>>>(Wq, Wk, Wv, Wt);
    xcast_kernel<<<dim3(4096), 256, 0, stream>>>(X, Xb);
    proj_fused<<<dim3(768), 256, 0, stream>>>(Xb, Wt, bq, bk, bv, Qb, Kb, Vt);
    int grid_c = direct ? 1 : max_chunks;
    attn_partial<<<dim3(128, grid_c), 128, 0, stream>>>(
        Qb, Kb, Vt, OpartH, Mpart, Lpart, O, chunk_tiles, max_chunks, direct);
    if (!direct)
        attn_merge<<<dim3(NT), 256, 0, stream>>>(OpartH, Mpart, Lpart, O,
                                                 chunk_tiles, max_chunks);
}